// Round 8
// baseline (366.441 us; speedup 1.0000x reference)
//
#include <hip/hip_runtime.h>
#include <hip/hip_bf16.h>
#include <stdint.h>

#define M_NODES 100000
#define E_EDGES 500000
#define NCOL    512      // U(256) | V(256)
#define HID     256

typedef unsigned short u16;
typedef u16   u16x8 __attribute__((ext_vector_type(8)));
typedef u16   u16x4 __attribute__((ext_vector_type(4)));
typedef __bf16 bf16x8 __attribute__((ext_vector_type(8)));
typedef float f32x4 __attribute__((ext_vector_type(4)));

static __device__ __forceinline__ u16 f2bf(float f) {
  uint32_t u = __float_as_uint(f);
  u += 0x7fff + ((u >> 16) & 1);      // RNE
  return (u16)(u >> 16);
}
static __device__ __forceinline__ float bf2f(u16 h) {
  return __uint_as_float(((uint32_t)h) << 16);
}

// Column permutation (within each 64-col block): storage s <-> logical n
//   n = nt*16 + lk*4 + r   <->   s = lk*16 + nt*4 + r     (involution)
// UV is stored permuted; k_edge permutes its W2 register load to match.
static __device__ __forceinline__ int col_perm(int p) {
  return (p & ~63) + ((p >> 2) & 3) * 16 + ((p >> 4) & 3) * 4 + (p & 3);
}

// ---------------- kernel 1: build Bt [512][128] bf16 (linear) ----------------
// Bt[j][k] = (j<256) ? W1[j][k] : W1[j-256][128+k]
__global__ __launch_bounds__(256) void k_weights(const float* __restrict__ W1,
                                                 u16* __restrict__ Bt) {
  int idx = blockIdx.x * 256 + threadIdx.x;   // 0..65535
  int j = idx >> 7, k = idx & 127;
  float w = (j < HID) ? W1[j * 256 + k] : W1[(j - HID) * 256 + 128 + k];
  Bt[idx] = f2bf(w);
}

// ---------------- kernel 2: fused convert+GEMM -------------------------------
// UV[m][s] = latent[m][:] . Bt[perm(s)][:]  (+b1 for logical col < 256)
// 8 waves/block, BM=64 x N=512; B fragments in VGPRs; A staged fp32->bf16 into
// 16KB XOR-swizzled LDS; 1 barrier. launch_bounds(512,6) -> 3 blocks/CU so
// cross-block overlap hides staging latency + barrier drain (round-5: (512,2)
// was 1 block/CU, 17.6% occupancy).
__global__ __launch_bounds__(512, 6) void k_gemm(const float* __restrict__ latent,
                                                 const u16* __restrict__ Bt,
                                                 const float* __restrict__ b1,
                                                 u16* __restrict__ UV) {
  __shared__ __align__(16) u16 ldsA[64 * 128];   // 16 KB
  const int t  = threadIdx.x;
  const int w  = t >> 6;          // wave 0..7
  const int l  = t & 63;
  const int lr = l & 15;
  const int lk = l >> 4;          // 0..3
  const int bm = blockIdx.x;      // 64-row tile index

  // ---- B fragments: fb[nt][ks], logical col n = w*64 + nt*16 + lr ----
  bf16x8 fb[4][4];
  {
    const u16* bp = Bt + ((size_t)(w * 64 + lr)) * 128 + lk * 8;
    #pragma unroll
    for (int nt = 0; nt < 4; ++nt)
      #pragma unroll
      for (int ks = 0; ks < 4; ++ks)
        fb[nt][ks] = *reinterpret_cast<const bf16x8*>(bp + nt * 16 * 128 + ks * 32);
  }

  // ---- stage A: 64 rows x 128 fp32 -> bf16 LDS, 16B-slot XOR swizzle ----
  {
    const float4* lat4 = reinterpret_cast<const float4*>(latent);
    #pragma unroll
    for (int i = 0; i < 4; ++i) {
      int idx = i * 512 + t;            // 0..2047 over [64 rows][32 f4cols]
      int row = idx >> 5;
      int c4  = idx & 31;
      int grow = bm * 64 + row;
      if (grow >= M_NODES) grow = M_NODES - 1;
      float4 f = lat4[(size_t)grow * 32 + c4];
      u16x4 o;
      o[0] = f2bf(f.x); o[1] = f2bf(f.y); o[2] = f2bf(f.z); o[3] = f2bf(f.w);
      int ss = (c4 >> 1) ^ (row & 7);                 // swizzled 16B slot
      *reinterpret_cast<u16x4*>(&ldsA[row * 128 + ss * 8 + (c4 & 1) * 4]) = o;
    }
  }
  __syncthreads();

  // ---- compute: 64 MFMAs/wave ----
  f32x4 acc[4][4];                 // [nt][mt]
  #pragma unroll
  for (int i = 0; i < 4; ++i)
    #pragma unroll
    for (int j = 0; j < 4; ++j) acc[i][j] = f32x4{0.f, 0.f, 0.f, 0.f};

  #pragma unroll
  for (int ks = 0; ks < 4; ++ks) {
    bf16x8 fa[4];
    #pragma unroll
    for (int mt = 0; mt < 4; ++mt) {
      int row = mt * 16 + lr;
      int ss  = ((4 * ks + lk) ^ (row & 7));
      fa[mt] = *reinterpret_cast<const bf16x8*>(&ldsA[row * 128 + ss * 8]);
    }
    #pragma unroll
    for (int nt = 0; nt < 4; ++nt)
      #pragma unroll
      for (int mt = 0; mt < 4; ++mt)
        acc[nt][mt] = __builtin_amdgcn_mfma_f32_16x16x32_bf16(fb[nt][ks], fa[mt], acc[nt][mt], 0, 0, 0);
  }

  // ---- epilogue: lane (lr,lk) holds storage cols [w*64+lk*16, +16) of row m ----
  float b1v[16];
  #pragma unroll
  for (int e = 0; e < 16; ++e) {
    int nt = e >> 2, r = e & 3;
    int n = w * 64 + nt * 16 + lk * 4 + r;       // logical col
    b1v[e] = (n < HID) ? b1[n] : 0.f;
  }
  #pragma unroll
  for (int mt = 0; mt < 4; ++mt) {
    int mg = bm * 64 + mt * 16 + lr;
    if (mg < M_NODES) {
      u16* dst = &UV[(size_t)mg * NCOL + w * 64 + lk * 16];
      u16x8 o0, o1;
      #pragma unroll
      for (int e = 0; e < 8; ++e) {
        int nt = e >> 2, r = e & 3;
        o0[e] = f2bf(acc[nt][mt][r]     + b1v[e]);
        o1[e] = f2bf(acc[nt + 2][mt][r] + b1v[8 + e]);
      }
      *reinterpret_cast<u16x8*>(dst)     = o0;
      *reinterpret_cast<u16x8*>(dst + 8) = o1;
    }
  }
}

// ---------------- kernel 3: per-edge  sigmoid(W2 . relu(U[s]+V[d]) + b2) -----
// 16 lanes per edge, 2 edges per group per iter -> 8 outstanding 16B gathers
// per lane (2x MLP vs round 6). W2 register load permuted to match UV storage.
__global__ __launch_bounds__(256, 6) void k_edge(const u16* __restrict__ UV,
                                                 const int* __restrict__ src,
                                                 const int* __restrict__ dst,
                                                 const float* __restrict__ W2,
                                                 const float* __restrict__ b2p,
                                                 float* __restrict__ out) {
  const int t = threadIdx.x;
  const int l = t & 63;
  const int sub = l & 15;          // lane within edge group
  const int eg = l >> 4;           // edge slot 0..3 in wave
  const int wid = blockIdx.x * 4 + (t >> 6);
  const int nw = gridDim.x * 4;

  float w2r[16];
  #pragma unroll
  for (int i = 0; i < 16; ++i) w2r[i] = W2[col_perm(sub * 16 + i)];
  const float b2 = *b2p;

  // E_EDGES % 8 == 0; each wave handles 8 edges/iter (2 per 16-lane group)
  for (int e = wid * 8; e < E_EDGES; e += nw * 8) {
    const int s0 = src[e + eg];
    const int d0 = dst[e + eg];
    const int s1 = src[e + 4 + eg];
    const int d1 = dst[e + 4 + eg];
    const u16* pu0 = UV + (size_t)s0 * NCOL + sub * 16;
    const u16* pv0 = UV + (size_t)d0 * NCOL + HID + sub * 16;
    const u16* pu1 = UV + (size_t)s1 * NCOL + sub * 16;
    const u16* pv1 = UV + (size_t)d1 * NCOL + HID + sub * 16;
    u16x8 ua0 = *reinterpret_cast<const u16x8*>(pu0);
    u16x8 ub0 = *reinterpret_cast<const u16x8*>(pu0 + 8);
    u16x8 va0 = *reinterpret_cast<const u16x8*>(pv0);
    u16x8 vb0 = *reinterpret_cast<const u16x8*>(pv0 + 8);
    u16x8 ua1 = *reinterpret_cast<const u16x8*>(pu1);
    u16x8 ub1 = *reinterpret_cast<const u16x8*>(pu1 + 8);
    u16x8 va1 = *reinterpret_cast<const u16x8*>(pv1);
    u16x8 vb1 = *reinterpret_cast<const u16x8*>(pv1 + 8);
    float a0 = 0.f, a1 = 0.f;
    #pragma unroll
    for (int i = 0; i < 8; ++i) {
      float h0 = fmaxf(bf2f(ua0[i]) + bf2f(va0[i]), 0.f);
      a0 = fmaf(h0, w2r[i], a0);
      float h1 = fmaxf(bf2f(ua1[i]) + bf2f(va1[i]), 0.f);
      a1 = fmaf(h1, w2r[i], a1);
    }
    #pragma unroll
    for (int i = 0; i < 8; ++i) {
      float h0 = fmaxf(bf2f(ub0[i]) + bf2f(vb0[i]), 0.f);
      a0 = fmaf(h0, w2r[8 + i], a0);
      float h1 = fmaxf(bf2f(ub1[i]) + bf2f(vb1[i]), 0.f);
      a1 = fmaf(h1, w2r[8 + i], a1);
    }
    a0 += __shfl_xor(a0, 1, 64);
    a1 += __shfl_xor(a1, 1, 64);
    a0 += __shfl_xor(a0, 2, 64);
    a1 += __shfl_xor(a1, 2, 64);
    a0 += __shfl_xor(a0, 4, 64);
    a1 += __shfl_xor(a1, 4, 64);
    a0 += __shfl_xor(a0, 8, 64);
    a1 += __shfl_xor(a1, 8, 64);
    if (sub == 0) {
      out[e + eg]     = 1.0f / (1.0f + __expf(-(a0 + b2)));
      out[e + 4 + eg] = 1.0f / (1.0f + __expf(-(a1 + b2)));
    }
  }
}

extern "C" void kernel_launch(void* const* d_in, const int* in_sizes, int n_in,
                              void* d_out, int out_size, void* d_ws, size_t ws_size,
                              hipStream_t stream) {
  const float* latent = (const float*)d_in[0];   // [100000*128]
  const float* W1     = (const float*)d_in[1];   // [256*256]
  const float* b1     = (const float*)d_in[2];   // [256]
  const float* W2     = (const float*)d_in[3];   // [256]
  const float* b2     = (const float*)d_in[4];   // [1]
  const int*   eidx   = (const int*)d_in[5];     // [2*500000]

  char* ws = (char*)d_ws;
  u16* Btw = (u16*)ws;                 // 131,072 B
  u16* UV  = (u16*)(ws + 131072);      // 102,400,000 B

  k_weights<<<256, 256, 0, stream>>>(W1, Btw);
  k_gemm<<<(M_NODES + 63) / 64, 512, 0, stream>>>(latent, Btw, b1, UV);
  k_edge<<<2048, 256, 0, stream>>>(UV, eidx, eidx + E_EDGES, W2, b2, (float*)d_out);
}

// Round 15
// 259.570 us; speedup vs baseline: 1.4117x; 1.4117x over previous
//
#include <hip/hip_runtime.h>
#include <hip/hip_bf16.h>
#include <stdint.h>

#define M_NODES 100000
#define E_EDGES 500000
#define NCOL    512      // U(256) | V(256)
#define HID     256
#define NTILES  ((M_NODES + 63) / 64)   // 1563
#define GGEMM   512                     // persistent gemm grid (2 blocks/CU)

typedef unsigned short u16;
typedef u16   u16x8 __attribute__((ext_vector_type(8)));
typedef u16   u16x4 __attribute__((ext_vector_type(4)));
typedef __bf16 bf16x8 __attribute__((ext_vector_type(8)));
typedef float f32x4 __attribute__((ext_vector_type(4)));

static __device__ __forceinline__ u16 f2bf(float f) {
  uint32_t u = __float_as_uint(f);
  u += 0x7fff + ((u >> 16) & 1);      // RNE
  return (u16)(u >> 16);
}
static __device__ __forceinline__ float bf2f(u16 h) {
  return __uint_as_float(((uint32_t)h) << 16);
}

// Column permutation (within each 64-col block): storage s <-> logical n
//   n = nt*16 + lk*4 + r   <->   s = lk*16 + nt*4 + r     (involution)
// UV is stored permuted; k_edge permutes its W2/b1 register loads to match.
static __device__ __forceinline__ int col_perm(int p) {
  return (p & ~63) + ((p >> 2) & 3) * 16 + ((p >> 4) & 3) * 4 + (p & 3);
}

// ---------------- kernel 1: build Bt [512][128] bf16 (linear) ----------------
// Bt[j][k] = (j<256) ? W1[j][k] : W1[j-256][128+k]
__global__ __launch_bounds__(256) void k_weights(const float* __restrict__ W1,
                                                 u16* __restrict__ Bt) {
  int idx = blockIdx.x * 256 + threadIdx.x;   // 0..65535
  int j = idx >> 7, k = idx & 127;
  float w = (j < HID) ? W1[j * 256 + k] : W1[(j - HID) * 256 + 128 + k];
  Bt[idx] = f2bf(w);
}

// ---------------- kernel 2: persistent fused convert+GEMM --------------------
// UV[m][s] = latent[m][:] . Bt[perm(s)][:]   (b1 is folded in k_edge, NOT here)
// 512 persistent blocks x 512 thr (2 blocks/CU via (512,4): 128-VGPR cap; the
// round-8 (512,6)=85-cap spilled -> 350MB scratch traffic). Each block loops
// ~3 m-tiles: B fragments load ONCE per block (3x less L2 B-traffic), A-tile
// staging for t+1 overlaps MFMA of t through a 2x16KB LDS double-buffer.
// One barrier per iteration (write buf^1 while others may still read buf: safe).
__global__ __launch_bounds__(512, 4) void k_gemm(const float* __restrict__ latent,
                                                 const u16* __restrict__ Bt,
                                                 u16* __restrict__ UV) {
  __shared__ __align__(16) u16 ldsA[2][64 * 128];   // 2 x 16 KB
  const int t  = threadIdx.x;
  const int w  = t >> 6;          // wave 0..7
  const int l  = t & 63;
  const int lr = l & 15;
  const int lk = l >> 4;          // 0..3

  // ---- B fragments: fb[nt][ks] = Bt[w*64+nt*16+lr][ks*32+lk*8 ..+7], once ----
  bf16x8 fb[4][4];
  {
    const u16* bp = Bt + ((size_t)(w * 64 + lr)) * 128 + lk * 8;
    #pragma unroll
    for (int nt = 0; nt < 4; ++nt)
      #pragma unroll
      for (int ks = 0; ks < 4; ++ks)
        fb[nt][ks] = *reinterpret_cast<const bf16x8*>(bp + nt * 16 * 128 + ks * 32);
  }

  const int row_ = t >> 5;        // staging row 0..15 (x4 phases)
  const int c4_  = t & 31;        // staging float4-col 0..31
  const float4* lat4 = reinterpret_cast<const float4*>(latent);

  float4 st[4];                   // in-flight A staging registers (16 VGPR)

  int tile = blockIdx.x;
  if (tile >= NTILES) return;

  // prologue: stage tile -> regs -> LDS buf0
  #pragma unroll
  for (int i = 0; i < 4; ++i) {
    int row = i * 16 + row_;
    int grow = tile * 64 + row;
    if (grow >= M_NODES) grow = M_NODES - 1;
    st[i] = lat4[(size_t)grow * 32 + c4_];
  }
  #pragma unroll
  for (int i = 0; i < 4; ++i) {
    int row = i * 16 + row_;
    u16x4 o;
    o[0] = f2bf(st[i].x); o[1] = f2bf(st[i].y); o[2] = f2bf(st[i].z); o[3] = f2bf(st[i].w);
    int ss = (c4_ >> 1) ^ (row & 7);
    *reinterpret_cast<u16x4*>(&ldsA[0][row * 128 + ss * 8 + (c4_ & 1) * 4]) = o;
  }

  int cur = 0;
  while (true) {
    const int nxt = tile + GGEMM;
    const bool has = (nxt < NTILES);

    // issue next tile's global loads (overlap with this tile's compute)
    if (has) {
      #pragma unroll
      for (int i = 0; i < 4; ++i) {
        int row = i * 16 + row_;
        int grow = nxt * 64 + row;
        if (grow >= M_NODES) grow = M_NODES - 1;
        st[i] = lat4[(size_t)grow * 32 + c4_];
      }
    }

    __syncthreads();   // buf[cur] fully written & visible

    // ---- compute from ldsA[cur]: 64 MFMAs/wave ----
    f32x4 acc[4][4];
    #pragma unroll
    for (int i = 0; i < 4; ++i)
      #pragma unroll
      for (int j = 0; j < 4; ++j) acc[i][j] = f32x4{0.f, 0.f, 0.f, 0.f};

    #pragma unroll
    for (int ks = 0; ks < 4; ++ks) {
      bf16x8 fa[4];
      #pragma unroll
      for (int mt = 0; mt < 4; ++mt) {
        int row = mt * 16 + lr;
        int ss  = ((4 * ks + lk) ^ (row & 7));
        fa[mt] = *reinterpret_cast<const bf16x8*>(&ldsA[cur][row * 128 + ss * 8]);
      }
      #pragma unroll
      for (int nt = 0; nt < 4; ++nt)
        #pragma unroll
        for (int mt = 0; mt < 4; ++mt)
          acc[nt][mt] = __builtin_amdgcn_mfma_f32_16x16x32_bf16(fb[nt][ks], fa[mt], acc[nt][mt], 0, 0, 0);
    }

    // ---- epilogue: lane (lr,lk) owns storage cols [w*64+lk*16, +16) ----
    #pragma unroll
    for (int mt = 0; mt < 4; ++mt) {
      int mg = tile * 64 + mt * 16 + lr;
      if (mg < M_NODES) {
        u16* dst = &UV[(size_t)mg * NCOL + w * 64 + lk * 16];
        u16x8 o0, o1;
        #pragma unroll
        for (int e = 0; e < 8; ++e) {
          int nt = e >> 2, r = e & 3;
          o0[e] = f2bf(acc[nt][mt][r]);
          o1[e] = f2bf(acc[nt + 2][mt][r]);
        }
        *reinterpret_cast<u16x8*>(dst)     = o0;
        *reinterpret_cast<u16x8*>(dst + 8) = o1;
      }
    }

    if (!has) break;

    // ds_write next tile into the other buffer (all waves are past the barrier,
    // so nobody still reads buf[cur^1]; readers of buf[cur] are unaffected)
    #pragma unroll
    for (int i = 0; i < 4; ++i) {
      int row = i * 16 + row_;
      u16x4 o;
      o[0] = f2bf(st[i].x); o[1] = f2bf(st[i].y); o[2] = f2bf(st[i].z); o[3] = f2bf(st[i].w);
      int ss = (c4_ >> 1) ^ (row & 7);
      *reinterpret_cast<u16x4*>(&ldsA[cur ^ 1][row * 128 + ss * 8 + (c4_ & 1) * 4]) = o;
    }
    cur ^= 1;
    tile = nxt;
  }
}

// ---------------- kernel 3: per-edge  sigmoid(W2 . relu(U[s]+V[d]+b1) + b2) --
// Round-6 known-good structure (single edge per 16-lane group, 74us) + b1 fold
// (b1 no longer folded in the GEMM). W2/b1 register loads permuted to match
// UV's permuted column storage.
__global__ __launch_bounds__(256, 8) void k_edge(const u16* __restrict__ UV,
                                                 const int* __restrict__ src,
                                                 const int* __restrict__ dst,
                                                 const float* __restrict__ W2,
                                                 const float* __restrict__ b1,
                                                 const float* __restrict__ b2p,
                                                 float* __restrict__ out) {
  const int t = threadIdx.x;
  const int l = t & 63;
  const int sub = l & 15;          // lane within edge group
  const int eg = l >> 4;           // edge slot 0..3 in wave
  const int wid = blockIdx.x * 4 + (t >> 6);
  const int nw = gridDim.x * 4;

  float w2r[16], b1r[16];
  #pragma unroll
  for (int i = 0; i < 16; ++i) {
    int lc = col_perm(sub * 16 + i);   // logical col in [0,256)
    w2r[i] = W2[lc];
    b1r[i] = b1[lc];
  }
  const float b2 = *b2p;

  for (int e = wid * 4; e < E_EDGES; e += nw * 4) {
    const int s = src[e + eg];
    const int d = dst[e + eg];
    const u16* pu = UV + (size_t)s * NCOL + sub * 16;
    const u16* pv = UV + (size_t)d * NCOL + HID + sub * 16;
    u16x8 ua = *reinterpret_cast<const u16x8*>(pu);
    u16x8 ub = *reinterpret_cast<const u16x8*>(pu + 8);
    u16x8 va = *reinterpret_cast<const u16x8*>(pv);
    u16x8 vb = *reinterpret_cast<const u16x8*>(pv + 8);
    float a = 0.f;
    #pragma unroll
    for (int i = 0; i < 8; ++i) {
      float h = bf2f(ua[i]) + bf2f(va[i]) + b1r[i];
      h = fmaxf(h, 0.f);
      a = fmaf(h, w2r[i], a);
    }
    #pragma unroll
    for (int i = 0; i < 8; ++i) {
      float h = bf2f(ub[i]) + bf2f(vb[i]) + b1r[8 + i];
      h = fmaxf(h, 0.f);
      a = fmaf(h, w2r[8 + i], a);
    }
    a += __shfl_xor(a, 1, 64);
    a += __shfl_xor(a, 2, 64);
    a += __shfl_xor(a, 4, 64);
    a += __shfl_xor(a, 8, 64);
    if (sub == 0) {
      out[e + eg] = 1.0f / (1.0f + __expf(-(a + b2)));
    }
  }
}

extern "C" void kernel_launch(void* const* d_in, const int* in_sizes, int n_in,
                              void* d_out, int out_size, void* d_ws, size_t ws_size,
                              hipStream_t stream) {
  const float* latent = (const float*)d_in[0];   // [100000*128]
  const float* W1     = (const float*)d_in[1];   // [256*256]
  const float* b1     = (const float*)d_in[2];   // [256]
  const float* W2     = (const float*)d_in[3];   // [256]
  const float* b2     = (const float*)d_in[4];   // [1]
  const int*   eidx   = (const int*)d_in[5];     // [2*500000]

  char* ws = (char*)d_ws;
  u16* Btw = (u16*)ws;                 // 131,072 B
  u16* UV  = (u16*)(ws + 131072);      // 102,400,000 B

  k_weights<<<256, 256, 0, stream>>>(W1, Btw);
  k_gemm<<<GGEMM, 512, 0, stream>>>(latent, Btw, UV);
  k_edge<<<2048, 256, 0, stream>>>(UV, eidx, eidx + E_EDGES, W2, b1, b2, (float*)d_out);
}